// Round 1
// 114.453 us; speedup vs baseline: 1.0251x; 1.0251x over previous
//
#include <hip/hip_runtime.h>
#include <hip/hip_bf16.h>

typedef __attribute__((ext_vector_type(8))) short short8;
typedef __attribute__((ext_vector_type(4))) float f32x4;
typedef unsigned short u16;
typedef unsigned int u32;

// B=512, M=40, H=128, D=64, C=128.
// Factored algebra: out[c,d] = sum_m x0[m,d] * T_m[c,d],
//   T_m[c,d] = sum_h W[c,h,m] * xk[h,d]   (pure bf16 GEMM, K=H=128)
// Telescoped: T never zeroed; out += (s_m - s_{m+1}) * T_cum.
#define NB 512
#define NM 40
#define NH 128
#define ND 64
#define NC 128
#define KTOT 5120

__device__ __forceinline__ u16 f2bf_rne(float f) {
    u32 u = __float_as_uint(f);
    u32 r = u + 0x7FFFu + ((u >> 16) & 1u);
    return (u16)(r >> 16);
}

// W fp32 [C][h*40+m] -> bf16 W3 [n=m*16+t*4+q][c][8j], h = t*32+q*8+j.
// grid 256 = c(128) x mhalf(2); float4 loads (20 m per half = 5 float4 per h-row).
__global__ void w3_kernel(const float* __restrict__ W, u16* __restrict__ W3) {
    __shared__ u16 kbuf[NH * 20];          // [h][mo], m-half only
    const int c = blockIdx.x >> 1, mh = blockIdx.x & 1;
    const float* src = W + (size_t)c * KTOT + mh * 20;
    for (int i = threadIdx.x; i < NH * 5; i += 256) {   // i = h*5 + j4
        int h = i / 5, j4 = i % 5;
        float4 v = *(const float4*)(src + h * NM + j4 * 4);
        u16* kb = kbuf + h * 20 + j4 * 4;
        kb[0] = f2bf_rne(v.x); kb[1] = f2bf_rne(v.y);
        kb[2] = f2bf_rne(v.z); kb[3] = f2bf_rne(v.w);
    }
    __syncthreads();
    for (int i = threadIdx.x; i < 320; i += 256) {      // i = mo*16 + t*4 + q
        int mo = i >> 4, t = (i >> 2) & 3, q = i & 3;
        int n = (mh * 20 + mo) * 16 + t * 4 + q;
        union { short8 s8; u16 e[8]; } v;
#pragma unroll
        for (int j = 0; j < 8; ++j)
            v.e[j] = kbuf[(t * 32 + q * 8 + j) * 20 + mo];
        *(short8*)(W3 + ((size_t)n * 128 + c) * 8) = v.s8;
    }
}

// main: grid 256 (2 batches/block), 512 thr = 8 waves = bh x rh x mh.
// Wave: 64 rows (rh) x 64 cols (batch bh), m in [mh*20, mh*20+20).
// B-fragments streamed from LDS (double-buffered bC, frees 32 regs vs full
// register cache); A software-pipelined DEPTH-4 from L2 (circular aP[4]):
// consuming body u waits only on loads issued at body u-4 -> ~3 bodies
// (~900 cyc) of latency slack, covering contended-L2/HBM-miss latency at
// the register-bound 2-waves/SIMD occupancy.
__global__ void __launch_bounds__(512, 2) cin_main(
    const float* __restrict__ x0g, const float* __restrict__ xkg,
    const float* __restrict__ biasg, const u16* __restrict__ W3,
    float* __restrict__ out)
{
    // [0,34816) xkT bf16 [2][64][136] | [34816,56576) x0s f32 [2][40][68]
    // epilogue overlay: red f32 [4][64][68] = 69632 B | bias at 69632
    __shared__ __align__(16) char smem[70144];
    short* xkT    = (short*)smem;
    float* x0s    = (float*)(smem + 34816);
    float* red    = (float*)smem;
    float* bias_s = (float*)(smem + 69632);

    const int tid = threadIdx.x;
    const int w = tid >> 6, L = tid & 63;
    const int q = L >> 4, l16 = L & 15;
    const int bh = (w >> 2) & 1;    // batch within block
    const int rh = (w >> 1) & 1;    // row half (c)
    const int mh = w & 1;           // m half: [mh*20, mh*20+20)
    const size_t b0 = 2 * (size_t)blockIdx.x;

    // A frag (m,t,mt): shorts index m*16384 + t*4096 + q*1024 + c*8,
    // c = rh*64 + mt*16 + l16
    const u16* Ap = W3 + q * 1024 + (size_t)(rh * 64 + l16) * 8;
    const int m0 = mh * 20;

    short8 aP[4][4];                 // depth-4 circular A pipeline
    auto loadAstep = [&](int u2, short8* dst) {
        const size_t m = (size_t)(m0 + (u2 >> 2));
        const int tt = u2 & 3;
        const u16* p = Ap + m * 16384 + tt * 4096;
#pragma unroll
        for (int mt = 0; mt < 4; ++mt)
            dst[mt] = *(const short8*)(p + mt * 128);
    };
    // issued before prologue staging: latency hidden under it
    loadAstep(0, aP[0]);
    loadAstep(1, aP[1]);
    loadAstep(2, aP[2]);
    loadAstep(3, aP[3]);

    // ---- prologue: 2 batches xk -> bf16 xkT (transposed), x0 -> LDS, bias
    {
        for (int i = tid; i < 4096; i += 512) {       // (bn, h, d4)
            int bn = i >> 11, rem = i & 2047;
            int h = rem >> 4, d4 = (rem & 15) << 2;
            float4 v = *(const float4*)(xkg + (b0 + bn) * (NH * ND) + h * ND + d4);
            short* xT = xkT + bn * 8704;
            xT[(d4 + 0) * 136 + h] = (short)f2bf_rne(v.x);
            xT[(d4 + 1) * 136 + h] = (short)f2bf_rne(v.y);
            xT[(d4 + 2) * 136 + h] = (short)f2bf_rne(v.z);
            xT[(d4 + 3) * 136 + h] = (short)f2bf_rne(v.w);
        }
        for (int i = tid; i < 1280; i += 512) {       // (bn, m, d4)
            int bn = i / 640, rem = i % 640;
            int m = rem >> 4, d4 = (rem & 15) << 2;
            *(f32x4*)(x0s + bn * 2720 + m * 68 + d4) =
                *(const f32x4*)(x0g + (b0 + bn) * (NM * ND) + m * ND + d4);
        }
        if (tid < NC) bias_s[tid] = biasg[tid];
    }
    __syncthreads();

    const float* x0p = x0s + bh * 2720;      // [40][68]
    // B frag (t,n): byte addr = bofs + n*4352 + t*64 into xkT
    int bofs = bh * 17408 + l16 * 272 + q * 16;

    short8 bB[2][4];                 // double-buffered streamed B
    auto loadB = [&](int tt, short8* dst, int bo) {
        const char* bsrc = (const char*)xkT + bo + tt * 64;
#pragma unroll
        for (int n = 0; n < 4; ++n)
            dst[n] = *(const short8*)(bsrc + n * 4352);
    };
    loadB(0, bB[0], bofs);

    float s[4], sn[4];
#pragma unroll
    for (int n = 0; n < 4; ++n)
        s[n] = x0p[m0 * 68 + n * 16 + l16];

    f32x4 T[4][4] = {};      // cumulative GEMM acc
    f32x4 o[4][4] = {};      // scaled output acc

    auto body = [&](int u, bool lastB) {
        const int t = u & 3;
        short8* aC = aP[u & 3];
        const short8* bC = bB[u & 1];
        if (!lastB) {
            // opaque offset: blocks LICM re-promoting the 16 loop-invariant
            // B-frags back into 64 registers (would blow the 256-reg cap)
            asm volatile("" : "+v"(bofs));
            loadB((u + 1) & 3, bB[(u + 1) & 1], bofs);
        }
        if (t == 0) {
            const int m = m0 + (u >> 2);
#pragma unroll
            for (int n = 0; n < 4; ++n)
                sn[n] = (m < m0 + 19) ? x0p[(m + 1) * 68 + n * 16 + l16] : 0.f;
        }
#pragma unroll
        for (int n = 0; n < 4; ++n) {
            T[0][n] = __builtin_amdgcn_mfma_f32_16x16x32_bf16(aC[0], bC[n], T[0][n], 0, 0, 0);
            T[1][n] = __builtin_amdgcn_mfma_f32_16x16x32_bf16(aC[1], bC[n], T[1][n], 0, 0, 0);
            T[2][n] = __builtin_amdgcn_mfma_f32_16x16x32_bf16(aC[2], bC[n], T[2][n], 0, 0, 0);
            T[3][n] = __builtin_amdgcn_mfma_f32_16x16x32_bf16(aC[3], bC[n], T[3][n], 0, 0, 0);
        }
        // reload consumed slot for step u+4 (main loop only; tail pre-staged)
        if (u < 76) loadAstep(u + 4, aC);
        if (t == 3) {        // telescoped scale: out += (s_m - s_{m+1}) * T
#pragma unroll
            for (int n = 0; n < 4; ++n) {
                const float dd = s[n] - sn[n];
#pragma unroll
                for (int mt = 0; mt < 4; ++mt)
                    o[mt][n] += dd * T[mt][n];
                s[n] = sn[n];
            }
        }
    };

#pragma unroll 4
    for (int u = 0; u < 76; ++u)     // u = mi*4 + t
        body(u, false);
#pragma unroll
    for (int u = 76; u < 80; ++u)    // peeled last m: no A reload, sn = 0
        body(u, u == 79);

    // ---- epilogue: mh-pair reduce in LDS (col-major, b128, 2-way banks)
    __syncthreads();                          // xkT/x0s dead -> overlay
    float* myred = red + (bh * 2 + rh) * 4352;   // [64 d][68 c-stride]
    if (mh == 1) {
#pragma unroll
        for (int mt = 0; mt < 4; ++mt)
#pragma unroll
            for (int n = 0; n < 4; ++n) {
                int d = n * 16 + l16;
                *(f32x4*)(myred + d * 68 + mt * 16 + q * 4) = o[mt][n];
            }
    }
    __syncthreads();
    if (mh == 0) {
        float* op = out + (b0 + bh) * (NC * ND);
#pragma unroll
        for (int mt = 0; mt < 4; ++mt)
#pragma unroll
            for (int n = 0; n < 4; ++n) {
                int d = n * 16 + l16;
                f32x4 r = *(const f32x4*)(myred + d * 68 + mt * 16 + q * 4);
#pragma unroll
                for (int rr = 0; rr < 4; ++rr) {
                    int c = rh * 64 + mt * 16 + q * 4 + rr;
                    op[c * ND + d] = o[mt][n][rr] + r[rr] + bias_s[c];
                }
            }
    }
}

extern "C" void kernel_launch(void* const* d_in, const int* in_sizes, int n_in,
                              void* d_out, int out_size, void* d_ws, size_t ws_size,
                              hipStream_t stream) {
    const float* x0 = (const float*)d_in[0];
    const float* xk = (const float*)d_in[1];
    const float* W  = (const float*)d_in[2];
    const float* bi = (const float*)d_in[3];
    float* out = (float*)d_out;

    u16* W3 = (u16*)d_ws;                      // 655360 shorts = 1.31 MB

    w3_kernel<<<NC * 2, 256, 0, stream>>>(W, W3);
    cin_main<<<NB / 2, 512, 0, stream>>>(x0, xk, bi, W3, out);
}